// Round 1
// 470.394 us; speedup vs baseline: 1.0303x; 1.0303x over previous
//
#include <hip/hip_runtime.h>

typedef __attribute__((ext_vector_type(8))) _Float16 half8;
typedef __attribute__((ext_vector_type(4))) float f32x4;

#define NF       1024
#define BM       64
#define NTHREADS 1024     // 16 waves
#define NSLABS   8        // K slabs of 128
#define SLABK    128
#define WCOPY0   2048
#define WCOPYS   2040
#define WTOT     (WCOPY0 + 7 * WCOPYS)   // 16328 fp16 elements

// out[b,i] = mm*x + mm + x,  mm[b,i] = sum_j x[b,j] * w[(j-i) mod 1024]
// MFMA mapping: m->token row, n->output col i, k->j.
// B[k][n] = wext[1024 + k - i], wext[u] = w[u & 1023].
// 8 shifted LDS copies of wext give every lane a 16B-aligned ds_read_b128.
// Circulant shift identity: B(f, k0+32) = B(f-2, k0)  ->  keep 4 B-frags in a
// register rotation, only 2 fresh B ds_reads per 32-k step.
// 16 waves, wave tile 64x64: acc = 64 VGPRs -> 4 waves/SIMD occupancy.
__global__ __launch_bounds__(NTHREADS, 4)
void circ_kernel(const float* __restrict__ x, const float* __restrict__ wsrc,
                 float* __restrict__ out) {
    // A tile: [128 windows of k>>3][64 rows][8 k-elems], fp16: 128 KiB
    __shared__ __align__(16) _Float16 lds_A[128 * 64 * 8];
    __shared__ __align__(16) _Float16 lds_W[WTOT];            // ~31.9 KiB

    const int tid  = threadIdx.x;
    const int bm   = blockIdx.x;        // 64-row tile index
    const int lane = tid & 63;
    const int wv   = tid >> 6;          // wave 0..15 -> cols [wv*64, +64)
    const int l15  = lane & 15;         // MFMA m (A) / n (B,C) index
    const int quad = lane >> 4;         // MFMA k-block (A,B) / row-block (C)

    // ---- stage 8 shifted copies of circulant weights (fp16) ----
    for (int idx = tid; idx < WTOT; idx += NTHREADS) {
        int s, t;
        if (idx < WCOPY0) { s = 0; t = idx; }
        else { int r = idx - WCOPY0; s = 1 + r / WCOPYS; t = r - (s - 1) * WCOPYS; }
        lds_W[idx] = (_Float16)wsrc[(t + s) & (NF - 1)];
    }

    // ---- A staging: thread -> (row sr, 8-col chunk skc), 8 floats each ----
    const int sr  = tid >> 4;           // 0..63
    const int skc = tid & 15;           // 0..15
    const float* xrow = x + ((size_t)(bm * BM + sr) << 10) + skc * 8;

    f32x4 st0 = *(const f32x4*)(xrow);
    f32x4 st1 = *(const f32x4*)(xrow + 4);

    auto write_slab = [&](int slab) {
        half8 h;
        #pragma unroll
        for (int e = 0; e < 4; ++e) h[e]     = (_Float16)st0[e];
        #pragma unroll
        for (int e = 0; e < 4; ++e) h[4 + e] = (_Float16)st1[e];
        int w = slab * 16 + skc;
        *(half8*)&lds_A[(w * 64 + sr) * 8] = h;
    };
    write_slab(0);

    // ---- B base offset for logical frag 0; frag f = bbase0 - 16*f + k0 ----
    // (copy selector s = o0 & 7 is invariant in f since 16*f % 8 == 0)
    int bbase0;
    {
        int icol = wv * 64 + l15;               // f = 0 column
        int o0   = 1024 + 8 * quad - icol;
        int s    = o0 & 7;
        int t0   = o0 - s;
        int offs = (s == 0) ? 0 : (WCOPY0 + (s - 1) * WCOPYS);
        bbase0 = offs + t0;
    }

    f32x4 acc[4][4];
    #pragma unroll
    for (int a = 0; a < 4; ++a)
        #pragma unroll
        for (int b = 0; b < 4; ++b)
            acc[a][b] = (f32x4){0.f, 0.f, 0.f, 0.f};

    __syncthreads();

    // ---- initial fill of the B rotation registers (logical f at k0 = 0) ----
    half8 bfr[4];
    #pragma unroll
    for (int f = 0; f < 4; ++f)
        bfr[f] = *(const half8*)&lds_W[bbase0 - 16 * f];

    for (int slab = 0; slab < NSLABS; ++slab) {
        if (slab + 1 < NSLABS) {                 // prefetch next slab -> regs
            const float* xs = xrow + (slab + 1) * SLABK;
            st0 = *(const f32x4*)(xs);
            st1 = *(const f32x4*)(xs + 4);
        }
        #pragma unroll
        for (int ks = 0; ks < 4; ++ks) {
            const int k0 = slab * SLABK + ks * 32;
            half8 afr[4];
            #pragma unroll
            for (int mf = 0; mf < 4; ++mf)
                afr[mf] = *(const half8*)&lds_A[(((k0 >> 3) + quad) * 64 + mf * 16 + l15) * 8];
            // logical f order {2,3,0,1}: fresh-loaded frags (0,1) consumed last
            constexpr int ford[4] = {2, 3, 0, 1};
            #pragma unroll
            for (int mf = 0; mf < 4; ++mf)
                #pragma unroll
                for (int ff = 0; ff < 4; ++ff) {
                    const int f = ford[ff];
                    acc[mf][f] = __builtin_amdgcn_mfma_f32_16x16x32_f16(
                        afr[mf], bfr[(f - 2 * ks) & 3], acc[mf][f], 0, 0, 0);
                }
            if (ks < 3) {                        // fresh B frags for next kstep
                const int k0n = k0 + 32;
                bfr[(0 - 2 * (ks + 1)) & 3] = *(const half8*)&lds_W[bbase0 + k0n];
                bfr[(1 - 2 * (ks + 1)) & 3] = *(const half8*)&lds_W[bbase0 - 16 + k0n];
            }
        }
        if (slab + 1 < NSLABS) {
            const int k0n = (slab + 1) * SLABK;  // fresh B frags for next slab
            bfr[0] = *(const half8*)&lds_W[bbase0 + k0n];
            bfr[1] = *(const half8*)&lds_W[bbase0 - 16 + k0n];
            write_slab(slab + 1);                // cvt + ds_write after compute
        }
        __syncthreads();
    }

    // ---- epilogue: out = mm*x + mm + x ; x re-read from resident LDS A ----
    #pragma unroll
    for (int mf = 0; mf < 4; ++mf) {
        #pragma unroll
        for (int f = 0; f < 4; ++f) {
            int icol = wv * 64 + f * 16 + l15;
            f32x4 v = acc[mf][f];
            #pragma unroll
            for (int reg = 0; reg < 4; ++reg) {
                int m = mf * 16 + quad * 4 + reg;    // C/D row = quad*4+reg
                float xf = (float)lds_A[((icol >> 3) * 64 + m) * 8 + (icol & 7)];
                float mm = v[reg];
                out[((size_t)(bm * BM + m) << 10) + icol] = mm * xf + mm + xf;
            }
        }
    }
}

extern "C" void kernel_launch(void* const* d_in, const int* in_sizes, int n_in,
                              void* d_out, int out_size, void* d_ws, size_t ws_size,
                              hipStream_t stream) {
    const float* x = (const float*)d_in[0];
    const float* w = (const float*)d_in[1];
    float* o       = (float*)d_out;
    circ_kernel<<<dim3(65536 / BM), dim3(NTHREADS), 0, stream>>>(x, w, o);
}